// Round 1
// baseline (1453.366 us; speedup 1.0000x reference)
//
#include <hip/hip_runtime.h>
#include <hip/hip_bf16.h>
#include <stdint.h>

#define E_N 150000
#define IN 512
#define HEADS 8
#define DK 64
#define MAXLEN 240

// padded perm sizes (64-aligned upper bounds)
#define PT 150272   // E + 4 types * 63 pad, rounded to 64
#define PE 150528   // E + 8 types * 63 pad, rounded to 64

typedef __attribute__((ext_vector_type(8))) short short8;
typedef __attribute__((ext_vector_type(4))) short short4v;
typedef __attribute__((ext_vector_type(4))) float f32x4;

// ---------- ws layout (bytes) ----------
#define OFF_R    0UL                       // float [240][512]      491520
#define OFF_WC   491520UL                  // bf16  [4][1024][512]  4194304
#define OFF_BIAS 4685824UL                 // float [4][1024]       16384
#define OFF_CNT  4702208UL                 // int   [64]            256
#define OFF_PT   4702464UL                 // int   [PT]            601088
#define OFF_PE   5303552UL                 // int   [PE]            602112
#define OFF_KS   5905664UL                 // bf16  [E][512]        153600000
// total ~159.5 MB

static __device__ __forceinline__ short f2bf(float f) {
  union { float f; uint32_t u; } v; v.f = f;
  uint32_t u = v.u;
  uint32_t r = (u + 0x7fffu + ((u >> 16) & 1u)) >> 16;
  return (short)r;
}
static __device__ __forceinline__ float bf2f(uint32_t bits16) {
  union { uint32_t u; float f; } v; v.u = bits16 << 16;
  return v.f;
}

// R[p][o] = sum_i emb[p][i]*linW[o][i] + linB[o]
__global__ __launch_bounds__(256) void k_rte(const float* __restrict__ emb,
    const float* __restrict__ linW, const float* __restrict__ linB,
    float* __restrict__ R) {
  __shared__ float x[IN];
  int p = blockIdx.x;
  for (int i = threadIdx.x; i < IN; i += 256) x[i] = emb[p * IN + i];
  __syncthreads();
  for (int o = threadIdx.x; o < IN; o += 256) {
    const float* w = linW + (long)o * IN;
    float s = 0.f;
#pragma unroll 4
    for (int k = 0; k < IN; k += 4) {
      float4 wv = *(const float4*)(w + k);
      s += wv.x * x[k] + wv.y * x[k + 1] + wv.z * x[k + 2] + wv.w * x[k + 3];
    }
    R[p * IN + o] = s + linB[o];
  }
}

// Wc[t][o][k] bf16: o<512 -> K_W[t][o][k], else V_W[t][o-512][k]
__global__ __launch_bounds__(256) void k_cvtw(const float* __restrict__ KW,
    const float* __restrict__ VW, short* __restrict__ Wc) {
  long idx = ((long)blockIdx.x * 256 + threadIdx.x) * 4;  // 4 elems each, total 2097152
  int t = (int)(idx >> 19);
  int rem = (int)(idx & ((1 << 19) - 1));
  int o = rem >> 9;
  int k = rem & 511;
  const float* src = (o < 512) ? (KW + ((long)(t * 512 + o) * 512) + k)
                               : (VW + ((long)(t * 512 + (o - 512)) * 512) + k);
  float4 v = *(const float4*)src;
  short4v b;
  b.x = f2bf(v.x); b.y = f2bf(v.y); b.z = f2bf(v.z); b.w = f2bf(v.w);
  *(short4v*)(Wc + idx) = b;
}

__global__ __launch_bounds__(256) void k_cvtb(const float* __restrict__ Kb,
    const float* __restrict__ Vb, float* __restrict__ biasC) {
  int idx = blockIdx.x * 256 + threadIdx.x;  // 4096 total
  int t = idx >> 10;
  int o = idx & 1023;
  biasC[idx] = (o < 512) ? Kb[t * 512 + o] : Vb[t * 512 + (o - 512)];
}

__global__ __launch_bounds__(256) void k_hist(const int* __restrict__ tau,
    const int* __restrict__ et, int* __restrict__ cnt) {
  __shared__ int l[12];
  if (threadIdx.x < 12) l[threadIdx.x] = 0;
  __syncthreads();
  int e = blockIdx.x * 256 + threadIdx.x;
  if (e < E_N) {
    atomicAdd(&l[tau[e]], 1);
    atomicAdd(&l[4 + et[e]], 1);
  }
  __syncthreads();
  if (threadIdx.x < 12) atomicAdd(&cnt[threadIdx.x], l[threadIdx.x]);
}

// c: [0..3]=cnt_tau [4..11]=cnt_et [12..15]=base_tau [16..23]=base_et [24..27]=cur_tau [28..35]=cur_et
__global__ void k_bases(int* c) {
  int b = 0;
  for (int t = 0; t < 4; t++) { c[12 + t] = b; b += ((c[t] + 63) >> 6) << 6; }
  b = 0;
  for (int g = 0; g < 8; g++) { c[16 + g] = b; b += ((c[4 + g] + 63) >> 6) << 6; }
  for (int i = 24; i < 36; i++) c[i] = 0;
}

__global__ __launch_bounds__(256) void k_scatter(const int* __restrict__ tau,
    const int* __restrict__ et, int* __restrict__ c,
    int* __restrict__ permT, int* __restrict__ permE) {
  __shared__ int lc[12], lbase[12];
  if (threadIdx.x < 12) lc[threadIdx.x] = 0;
  __syncthreads();
  int e = blockIdx.x * 256 + threadIdx.x;
  bool v = e < E_N;
  int t = 0, g = 0, pt = 0, pe = 0;
  if (v) {
    t = tau[e]; g = et[e];
    pt = atomicAdd(&lc[t], 1);
    pe = atomicAdd(&lc[4 + g], 1);
  }
  __syncthreads();
  if (threadIdx.x < 12) {
    int n = lc[threadIdx.x];
    int base = 0;
    if (n > 0) {
      if (threadIdx.x < 4) base = atomicAdd(&c[24 + threadIdx.x], n);
      else                 base = atomicAdd(&c[28 + (threadIdx.x - 4)], n);
    }
    lbase[threadIdx.x] = base;
  }
  __syncthreads();
  if (v) {
    permT[c[12 + t] + lbase[t] + pt] = e;
    permE[c[16 + g] + lbase[4 + g] + pe] = e;
  }
}

// Stage-1: per 64-edge (tau-uniform) block, C[64 x 512] = h_hat(bf16) @ Wc[t]^half + bias
// blockIdx.y==0 -> K_s (bf16 to ws), ==1 -> V_s (f32 into d_out M region)
__global__ __launch_bounds__(512, 1) void k_gemm(
    const float* __restrict__ hs, const float* __restrict__ R,
    const int* __restrict__ dt, const int* __restrict__ tau,
    const short* __restrict__ Wc, const float* __restrict__ biasC,
    const int* __restrict__ perm,
    short* __restrict__ Ks, float* __restrict__ Mout) {
  __shared__ short sA[64][40];  // padded stride 40 shorts (80B)
  __shared__ int eRow[64];
  __shared__ int dtRow[64];
  __shared__ int metaT;
  int tid = threadIdx.x;
  int m0 = blockIdx.x * 64;
  if (tid < 64) {
    int e = perm[m0 + tid];
    eRow[tid] = e;
    dtRow[tid] = (e >= 0) ? dt[e] : 0;
  }
  __syncthreads();
  if (tid == 0) {
    int t = -1;
    for (int i = 0; i < 64; i++)
      if (eRow[i] >= 0) { t = tau[eRow[i]]; break; }
    metaT = t;
  }
  __syncthreads();
  int t = metaT;
  if (t < 0) return;  // fully-padded tail block (uniform)

  int lane = tid & 63;
  int wv = tid >> 6;
  int oWave = blockIdx.y * 512 + wv * 64;
  int l15 = lane & 15;
  int lk8 = (lane >> 4) * 8;

  f32x4 acc[4][4] = {};

  // staging assignment: thread -> (row, 4 k-elems)
  int srow = tid >> 3;
  int skq = (tid & 7) * 4;
  int sE = eRow[srow];
  const float* hsrc = hs + (long)(sE >= 0 ? sE : 0) * IN + skq;
  const float* rsrc = R + (long)dtRow[srow] * IN + skq;

  const short* wbase = Wc + ((long)t * 1024 + oWave + l15) * IN + lk8;

  float4 hv = {0, 0, 0, 0}, rv = {0, 0, 0, 0};
  if (sE >= 0) { hv = *(const float4*)hsrc; rv = *(const float4*)rsrc; }

  for (int kk = 0; kk < 16; kk++) {
    int k0 = kk * 32;
    short4v sv;
    sv.x = f2bf(hv.x + rv.x);
    sv.y = f2bf(hv.y + rv.y);
    sv.z = f2bf(hv.z + rv.z);
    sv.w = f2bf(hv.w + rv.w);
    *(short4v*)&sA[srow][skq] = sv;
    if (kk < 15 && sE >= 0) {  // prefetch next K-step
      hv = *(const float4*)(hsrc + (kk + 1) * 32);
      rv = *(const float4*)(rsrc + (kk + 1) * 32);
    }
    __syncthreads();
    short8 a[4], b[4];
#pragma unroll
    for (int mi = 0; mi < 4; mi++)
      a[mi] = *(const short8*)&sA[mi * 16 + l15][lk8];
#pragma unroll
    for (int ni = 0; ni < 4; ni++)
      b[ni] = *(const short8*)(wbase + (long)ni * 16 * IN + k0);
#pragma unroll
    for (int mi = 0; mi < 4; mi++)
#pragma unroll
      for (int ni = 0; ni < 4; ni++)
        acc[mi][ni] = __builtin_amdgcn_mfma_f32_16x16x32_bf16(a[mi], b[ni], acc[mi][ni], 0, 0, 0);
    __syncthreads();
  }

  // epilogue: D row=(lane>>4)*4+reg, col=lane&15
  int rbase = (lane >> 4) * 4;
  bool isK = (blockIdx.y == 0);
#pragma unroll
  for (int mi = 0; mi < 4; mi++) {
#pragma unroll
    for (int r = 0; r < 4; r++) {
      int row = mi * 16 + rbase + r;
      int e = eRow[row];
      if (e < 0) continue;
#pragma unroll
      for (int ni = 0; ni < 4; ni++) {
        int col = oWave + ni * 16 + l15;
        float v = acc[mi][ni][r] + biasC[t * 1024 + col];
        if (isK) Ks[(long)e * IN + col] = f2bf(v);
        else     Mout[(long)e * IN + (col - 512)] = v;
      }
    }
  }
}

// Stage-2: per 64-edge (etype-uniform) block: M = Wmsg V_s, att = (Q . Watt K_s) * mu / 8
__global__ __launch_bounds__(256) void k_stage2(
    const int* __restrict__ perm, const int* __restrict__ et,
    const float* __restrict__ WattW, const float* __restrict__ WmsgW,
    const float* __restrict__ Qt, const float* __restrict__ mu,
    const short* __restrict__ Ks, float* __restrict__ Mout,
    float* __restrict__ attOut) {
  __shared__ float WaT[64][66];  // transposed [j][d], padded
  __shared__ float WmT[64][66];
  __shared__ float vsl[512];
  __shared__ float qsl[512];
  __shared__ float ksl[512];
  __shared__ int eArr[64];
  __shared__ int metaG;
  int tid = threadIdx.x;
  int m0 = blockIdx.x * 64;
  if (tid < 64) eArr[tid] = perm[m0 + tid];
  __syncthreads();
  if (tid == 0) {
    int g = -1;
    for (int i = 0; i < 64; i++)
      if (eArr[i] >= 0) { g = et[eArr[i]]; break; }
    metaG = g;
  }
  __syncthreads();
  int g = metaG;
  if (g < 0) return;

  for (int i = tid; i < 4096; i += 256) {
    int d = i >> 6, j = i & 63;
    WaT[j][d] = WattW[(long)g * 4096 + i];
    WmT[j][d] = WmsgW[(long)g * 4096 + i];
  }
  __syncthreads();

  int h = tid >> 5;
  int d0 = (tid & 31) * 2;
  float muh = mu[g * 8 + h];

  for (int i = 0; i < 64; i++) {
    int e = eArr[i];
    if (e < 0) continue;  // uniform per block
    {
      float2 v2 = *(const float2*)(Mout + (long)e * 512 + tid * 2);
      ((float2*)vsl)[tid] = v2;
      float2 q2 = *(const float2*)(Qt + (long)e * 512 + tid * 2);
      ((float2*)qsl)[tid] = q2;
      uint32_t k2 = *(const uint32_t*)(Ks + (long)e * 512 + tid * 2);
      ksl[tid * 2]     = bf2f(k2 & 0xffffu);
      ksl[tid * 2 + 1] = bf2f(k2 >> 16);
    }
    __syncthreads();
    const float* vrow = &vsl[h * 64];
    const float* krow = &ksl[h * 64];
    float m0v = 0.f, m1v = 0.f, a0 = 0.f, a1 = 0.f;
#pragma unroll 8
    for (int j = 0; j < 64; j++) {
      float v = vrow[j], k = krow[j];
      float2 wm = *(const float2*)&WmT[j][d0];
      float2 wa = *(const float2*)&WaT[j][d0];
      m0v += wm.x * v; m1v += wm.y * v;
      a0  += wa.x * k; a1  += wa.y * k;
    }
    __syncthreads();  // vs/ks/qs consumed; safe to overwrite next iter
    float2 mo; mo.x = m0v; mo.y = m1v;
    *(float2*)(Mout + (long)e * 512 + h * 64 + d0) = mo;
    float s = qsl[h * 64 + d0] * a0 + qsl[h * 64 + d0 + 1] * a1;
    s += __shfl_xor(s, 16);
    s += __shfl_xor(s, 8);
    s += __shfl_xor(s, 4);
    s += __shfl_xor(s, 2);
    s += __shfl_xor(s, 1);
    if ((tid & 31) == 0) attOut[(long)e * 8 + h] = s * muh * 0.125f;
  }
}

extern "C" void kernel_launch(void* const* d_in, const int* in_sizes, int n_in,
                              void* d_out, int out_size, void* d_ws, size_t ws_size,
                              hipStream_t stream) {
  const float* hs    = (const float*)d_in[0];
  const float* Qt    = (const float*)d_in[1];
  const int*   et    = (const int*)d_in[2];
  const int*   tau   = (const int*)d_in[3];
  const int*   dt    = (const int*)d_in[4];
  const float* emb   = (const float*)d_in[5];
  const float* linW  = (const float*)d_in[6];
  const float* linB  = (const float*)d_in[7];
  const float* KW    = (const float*)d_in[8];
  const float* Kb    = (const float*)d_in[9];
  const float* VW    = (const float*)d_in[10];
  const float* Vb    = (const float*)d_in[11];
  const float* WattW = (const float*)d_in[12];
  const float* WmsgW = (const float*)d_in[13];
  const float* mu    = (const float*)d_in[14];

  char* ws = (char*)d_ws;
  float* R     = (float*)(ws + OFF_R);
  short* Wc    = (short*)(ws + OFF_WC);
  float* biasC = (float*)(ws + OFF_BIAS);
  int*   cnt   = (int*)(ws + OFF_CNT);
  int*   permT = (int*)(ws + OFF_PT);
  int*   permE = (int*)(ws + OFF_PE);
  short* Ks    = (short*)(ws + OFF_KS);

  float* attOut = (float*)d_out;
  float* Mout   = (float*)d_out + (long)E_N * 8;

  hipMemsetAsync(cnt, 0, 64 * sizeof(int), stream);
  hipMemsetAsync(permT, 0xFF, PT * sizeof(int), stream);
  hipMemsetAsync(permE, 0xFF, PE * sizeof(int), stream);

  k_rte<<<240, 256, 0, stream>>>(emb, linW, linB, R);
  k_cvtw<<<2048, 256, 0, stream>>>(KW, VW, Wc);
  k_cvtb<<<16, 256, 0, stream>>>(Kb, Vb, biasC);
  k_hist<<<(E_N + 255) / 256, 256, 0, stream>>>(tau, et, cnt);
  k_bases<<<1, 1, 0, stream>>>(cnt);
  k_scatter<<<(E_N + 255) / 256, 256, 0, stream>>>(tau, et, cnt, permT, permE);
  k_gemm<<<dim3(PT / 64, 2), 512, 0, stream>>>(hs, R, dt, tau, Wc, biasC, permT, Ks, Mout);
  k_stage2<<<PE / 64, 256, 0, stream>>>(permE, et, WattW, WmsgW, Qt, mu, Ks, Mout, attOut);
}

// Round 2
// 806.965 us; speedup vs baseline: 1.8010x; 1.8010x over previous
//
#include <hip/hip_runtime.h>
#include <hip/hip_bf16.h>
#include <stdint.h>

#define E_N 150000
#define IN 512
#define HEADS 8
#define DK 64
#define MAXLEN 240

// padded perm sizes (64-aligned upper bounds)
#define PT 150272   // E + 4 types * 63 pad, rounded to 64
#define PE 150528   // E + 8 types * 63 pad, rounded to 64

typedef __attribute__((ext_vector_type(8))) short short8;
typedef __attribute__((ext_vector_type(4))) short short4v;
typedef __attribute__((ext_vector_type(4))) float f32x4;

// ---------- ws layout (bytes) ----------
#define OFF_R    0UL                       // float [240][512]      491520
#define OFF_WC   491520UL                  // bf16  [4][1024][512]  4194304
#define OFF_BIAS 4685824UL                 // float [4][1024]       16384
#define OFF_CNT  4702208UL                 // int   [64]            256
#define OFF_PT   4702464UL                 // int   [PT]            601088
#define OFF_PE   5303552UL                 // int   [PE]            602112
#define OFF_KS   5905664UL                 // bf16  [E][512]        153600000
// total ~159.5 MB

static __device__ __forceinline__ short f2bf(float f) {
  union { float f; uint32_t u; } v; v.f = f;
  uint32_t u = v.u;
  uint32_t r = (u + 0x7fffu + ((u >> 16) & 1u)) >> 16;
  return (short)r;
}

// R[p][o] = sum_i emb[p][i]*linW[o][i] + linB[o]
__global__ __launch_bounds__(256) void k_rte(const float* __restrict__ emb,
    const float* __restrict__ linW, const float* __restrict__ linB,
    float* __restrict__ R) {
  __shared__ float x[IN];
  int p = blockIdx.x;
  for (int i = threadIdx.x; i < IN; i += 256) x[i] = emb[p * IN + i];
  __syncthreads();
  for (int o = threadIdx.x; o < IN; o += 256) {
    const float* w = linW + (long)o * IN;
    float s = 0.f;
#pragma unroll 4
    for (int k = 0; k < IN; k += 4) {
      float4 wv = *(const float4*)(w + k);
      s += wv.x * x[k] + wv.y * x[k + 1] + wv.z * x[k + 2] + wv.w * x[k + 3];
    }
    R[p * IN + o] = s + linB[o];
  }
}

// Wc[t][o][k] bf16: o<512 -> K_W[t][o][k], else V_W[t][o-512][k]
__global__ __launch_bounds__(256) void k_cvtw(const float* __restrict__ KW,
    const float* __restrict__ VW, short* __restrict__ Wc) {
  long idx = ((long)blockIdx.x * 256 + threadIdx.x) * 4;  // total 2097152
  int t = (int)(idx >> 19);
  int rem = (int)(idx & ((1 << 19) - 1));
  int o = rem >> 9;
  int k = rem & 511;
  const float* src = (o < 512) ? (KW + ((long)(t * 512 + o) * 512) + k)
                               : (VW + ((long)(t * 512 + (o - 512)) * 512) + k);
  float4 v = *(const float4*)src;
  short4v b;
  b.x = f2bf(v.x); b.y = f2bf(v.y); b.z = f2bf(v.z); b.w = f2bf(v.w);
  *(short4v*)(Wc + idx) = b;
}

__global__ __launch_bounds__(256) void k_cvtb(const float* __restrict__ Kb,
    const float* __restrict__ Vb, float* __restrict__ biasC) {
  int idx = blockIdx.x * 256 + threadIdx.x;  // 4096 total
  int t = idx >> 10;
  int o = idx & 1023;
  biasC[idx] = (o < 512) ? Kb[t * 512 + o] : Vb[t * 512 + (o - 512)];
}

__global__ __launch_bounds__(256) void k_hist(const int* __restrict__ tau,
    const int* __restrict__ et, int* __restrict__ cnt) {
  __shared__ int l[12];
  if (threadIdx.x < 12) l[threadIdx.x] = 0;
  __syncthreads();
  int e = blockIdx.x * 256 + threadIdx.x;
  if (e < E_N) {
    atomicAdd(&l[tau[e]], 1);
    atomicAdd(&l[4 + et[e]], 1);
  }
  __syncthreads();
  if (threadIdx.x < 12) atomicAdd(&cnt[threadIdx.x], l[threadIdx.x]);
}

// c: [0..3]=cnt_tau [4..11]=cnt_et [12..15]=base_tau [16..23]=base_et [24..27]=cur_tau [28..35]=cur_et
__global__ void k_bases(int* c) {
  int b = 0;
  for (int t = 0; t < 4; t++) { c[12 + t] = b; b += ((c[t] + 63) >> 6) << 6; }
  b = 0;
  for (int g = 0; g < 8; g++) { c[16 + g] = b; b += ((c[4 + g] + 63) >> 6) << 6; }
  for (int i = 24; i < 36; i++) c[i] = 0;
}

__global__ __launch_bounds__(256) void k_scatter(const int* __restrict__ tau,
    const int* __restrict__ et, int* __restrict__ c,
    int* __restrict__ permT, int* __restrict__ permE) {
  __shared__ int lc[12], lbase[12];
  if (threadIdx.x < 12) lc[threadIdx.x] = 0;
  __syncthreads();
  int e = blockIdx.x * 256 + threadIdx.x;
  bool v = e < E_N;
  int t = 0, g = 0, pt = 0, pe = 0;
  if (v) {
    t = tau[e]; g = et[e];
    pt = atomicAdd(&lc[t], 1);
    pe = atomicAdd(&lc[4 + g], 1);
  }
  __syncthreads();
  if (threadIdx.x < 12) {
    int n = lc[threadIdx.x];
    int base = 0;
    if (n > 0) {
      if (threadIdx.x < 4) base = atomicAdd(&c[24 + threadIdx.x], n);
      else                 base = atomicAdd(&c[28 + (threadIdx.x - 4)], n);
    }
    lbase[threadIdx.x] = base;
  }
  __syncthreads();
  if (v) {
    permT[c[12 + t] + lbase[t] + pt] = e;
    permE[c[16 + g] + lbase[4 + g] + pe] = e;
  }
}

// Stage-1: per 64-edge (tau-uniform) block, C[64 x 1024] = h_hat(bf16) @ Wc[t] + bias
// cols 0..511 -> K_s (bf16, ws); cols 512..1023 -> V_s (bf16, second half of each M slot in d_out)
__global__ __launch_bounds__(512, 1) void k_gemm(
    const float* __restrict__ hs, const float* __restrict__ R,
    const int* __restrict__ dt, const int* __restrict__ tau,
    const short* __restrict__ Wc, const float* __restrict__ biasC,
    const int* __restrict__ perm,
    short* __restrict__ Ks, float* Mout) {
  __shared__ short sA[64][40];  // padded stride 40 shorts (80B)
  __shared__ int eRow[64];
  __shared__ int dtRow[64];
  __shared__ int metaT;
  int tid = threadIdx.x;
  int m0 = blockIdx.x * 64;
  if (tid < 64) {
    int e = perm[m0 + tid];
    eRow[tid] = e;
    dtRow[tid] = (e >= 0) ? dt[e] : 0;
  }
  __syncthreads();
  if (tid == 0) {
    int t = -1;
    for (int i = 0; i < 64; i++)
      if (eRow[i] >= 0) { t = tau[eRow[i]]; break; }
    metaT = t;
  }
  __syncthreads();
  int t = metaT;
  if (t < 0) return;  // fully-padded tail block (uniform)

  int lane = tid & 63;
  int wv = tid >> 6;
  int oWave = wv * 128;            // each of 8 waves owns 128 output cols
  int l15 = lane & 15;
  int lk8 = (lane >> 4) * 8;

  f32x4 acc[4][8] = {};

  // staging assignment: thread -> (row, 4 k-elems)
  int srow = tid >> 3;
  int skq = (tid & 7) * 4;
  int sE = eRow[srow];
  const float* hsrc = hs + (long)(sE >= 0 ? sE : 0) * IN + skq;
  const float* rsrc = R + (long)dtRow[srow] * IN + skq;

  const short* wbase = Wc + ((long)t * 1024 + oWave + l15) * IN + lk8;

  float4 hv = {0, 0, 0, 0}, rv = {0, 0, 0, 0};
  if (sE >= 0) { hv = *(const float4*)hsrc; rv = *(const float4*)rsrc; }

  for (int kk = 0; kk < 16; kk++) {
    int k0 = kk * 32;
    short4v sv;
    sv.x = f2bf(hv.x + rv.x);
    sv.y = f2bf(hv.y + rv.y);
    sv.z = f2bf(hv.z + rv.z);
    sv.w = f2bf(hv.w + rv.w);
    *(short4v*)&sA[srow][skq] = sv;
    if (kk < 15 && sE >= 0) {  // prefetch next K-step
      hv = *(const float4*)(hsrc + (kk + 1) * 32);
      rv = *(const float4*)(rsrc + (kk + 1) * 32);
    }
    __syncthreads();
    short8 a[4], b[8];
#pragma unroll
    for (int mi = 0; mi < 4; mi++)
      a[mi] = *(const short8*)&sA[mi * 16 + l15][lk8];
#pragma unroll
    for (int ni = 0; ni < 8; ni++)
      b[ni] = *(const short8*)(wbase + (long)ni * 16 * IN + k0);
#pragma unroll
    for (int mi = 0; mi < 4; mi++)
#pragma unroll
      for (int ni = 0; ni < 8; ni++)
        acc[mi][ni] = __builtin_amdgcn_mfma_f32_16x16x32_bf16(a[mi], b[ni], acc[mi][ni], 0, 0, 0);
    __syncthreads();
  }

  // epilogue: D row=(lane>>4)*4+reg, col=lane&15
  int rbase = (lane >> 4) * 4;
  float bias[8];
#pragma unroll
  for (int ni = 0; ni < 8; ni++)
    bias[ni] = biasC[t * 1024 + oWave + ni * 16 + l15];
#pragma unroll
  for (int mi = 0; mi < 4; mi++) {
#pragma unroll
    for (int r = 0; r < 4; r++) {
      int row = mi * 16 + rbase + r;
      int e = eRow[row];
      if (e < 0) continue;
      short* vdst = (short*)((char*)Mout + (size_t)e * 2048 + 1024);
#pragma unroll
      for (int ni = 0; ni < 8; ni++) {
        int col = oWave + ni * 16 + l15;
        float v = acc[mi][ni][r] + bias[ni];
        if (col < 512) Ks[(long)e * IN + col] = f2bf(v);
        else           vdst[col - 512] = f2bf(v);
      }
    }
  }
}

// Stage-2: batched MFMA GEMM over (e,h)-rows, 64 etype-uniform edges (512 rows) per block.
//   M    = V_s @ Wmsg[g]^T  (rows from in-place bf16 V slots in d_out; writes f32 M over them)
//   attk = K_s @ Watt[g]^T, att = (Q . attk) * mu / 8
__global__ __launch_bounds__(512, 1) void k_stage2(
    const int* __restrict__ perm, const int* __restrict__ et,
    const float* __restrict__ WattW, const float* __restrict__ WmsgW,
    const float* __restrict__ Qt, const float* __restrict__ mu,
    const short* __restrict__ Ks, float* Mout,
    float* __restrict__ attOut) {
  __shared__ short Wm[64][68];  // [o][i], pad to 68 shorts (136B stride)
  __shared__ short Wa[64][68];
  __shared__ float muL[8];
  __shared__ int eArr[64];
  __shared__ int metaG;
  int tid = threadIdx.x;
  int m0 = blockIdx.x * 64;
  if (tid < 64) eArr[tid] = perm[m0 + tid];
  __syncthreads();
  if (tid == 0) {
    int g = -1;
    for (int i = 0; i < 64; i++)
      if (eArr[i] >= 0) { g = et[eArr[i]]; break; }
    metaG = g;
  }
  __syncthreads();
  int g = metaG;
  if (g < 0) return;

  for (int i = tid; i < 4096; i += 512) {
    int o = i >> 6, k = i & 63;
    Wm[o][k] = f2bf(WmsgW[(long)g * 4096 + i]);
    Wa[o][k] = f2bf(WattW[(long)g * 4096 + i]);
  }
  if (tid < 8) muL[tid] = mu[g * 8 + tid];
  __syncthreads();

  int lane = tid & 63;
  int wv = tid >> 6;
  int wvBase = wv * 64;            // wave owns 64 rows = 8 edges
  int l15 = lane & 15;
  int lk8 = (lane >> 4) * 8;
  int rbase = (lane >> 4) * 4;

  // A-frag row ids (per-lane, row = wvBase + mi*16 + l15)
  int eA[4], hA[4];
#pragma unroll
  for (int mi = 0; mi < 4; mi++) {
    int lr = wvBase + mi * 16 + l15;
    int e = eArr[lr >> 3];
    eA[mi] = (e >= 0) ? e : 0;
    hA[mi] = lr & 7;
  }

  // ---- M = V @ Wmsg^T ----
  {
    short8 av[4][2];
#pragma unroll
    for (int mi = 0; mi < 4; mi++) {
      const short* vp = (const short*)((const char*)Mout + (size_t)eA[mi] * 2048 + 1024)
                        + hA[mi] * 64 + lk8;
      av[mi][0] = *(const short8*)vp;
      av[mi][1] = *(const short8*)(vp + 32);
    }
    short8 bm[4][2];
#pragma unroll
    for (int ni = 0; ni < 4; ni++)
#pragma unroll
      for (int kk = 0; kk < 2; kk++)
        bm[ni][kk] = *(const short8*)&Wm[ni * 16 + l15][kk * 32 + lk8];
    f32x4 accM[4][4] = {};
#pragma unroll
    for (int kk = 0; kk < 2; kk++)
#pragma unroll
      for (int mi = 0; mi < 4; mi++)
#pragma unroll
        for (int ni = 0; ni < 4; ni++)
          accM[mi][ni] = __builtin_amdgcn_mfma_f32_16x16x32_bf16(av[mi][kk], bm[ni][kk], accM[mi][ni], 0, 0, 0);
#pragma unroll
    for (int mi = 0; mi < 4; mi++) {
#pragma unroll
      for (int r = 0; r < 4; r++) {
        int lr = wvBase + mi * 16 + rbase + r;
        int e = eArr[lr >> 3];
        if (e < 0) continue;
        int h = lr & 7;
#pragma unroll
        for (int ni = 0; ni < 4; ni++)
          Mout[(long)e * 512 + h * 64 + ni * 16 + l15] = accM[mi][ni][r];
      }
    }
  }

  // ---- attk = K @ Watt^T ; att = (Q . attk) * mu / 8 ----
  {
    short8 ak[4][2];
#pragma unroll
    for (int mi = 0; mi < 4; mi++) {
      const short* kp = Ks + (long)eA[mi] * 512 + hA[mi] * 64 + lk8;
      ak[mi][0] = *(const short8*)kp;
      ak[mi][1] = *(const short8*)(kp + 32);
    }
    short8 ba[4][2];
#pragma unroll
    for (int ni = 0; ni < 4; ni++)
#pragma unroll
      for (int kk = 0; kk < 2; kk++)
        ba[ni][kk] = *(const short8*)&Wa[ni * 16 + l15][kk * 32 + lk8];
    f32x4 accA[4][4] = {};
#pragma unroll
    for (int kk = 0; kk < 2; kk++)
#pragma unroll
      for (int mi = 0; mi < 4; mi++)
#pragma unroll
        for (int ni = 0; ni < 4; ni++)
          accA[mi][ni] = __builtin_amdgcn_mfma_f32_16x16x32_bf16(ak[mi][kk], ba[ni][kk], accA[mi][ni], 0, 0, 0);
#pragma unroll
    for (int mi = 0; mi < 4; mi++) {
#pragma unroll
      for (int r = 0; r < 4; r++) {
        int lr = wvBase + mi * 16 + rbase + r;
        int e = eArr[lr >> 3];
        if (e < 0) continue;
        int h = lr & 7;
        const float* qp = Qt + ((long)e * 8 + h) * 64 + l15;
        float s = 0.f;
#pragma unroll
        for (int ni = 0; ni < 4; ni++)
          s += qp[ni * 16] * accA[mi][ni][r];
        s += __shfl_xor(s, 1);
        s += __shfl_xor(s, 2);
        s += __shfl_xor(s, 4);
        s += __shfl_xor(s, 8);
        if (l15 == 0) attOut[(long)e * 8 + h] = s * muL[h] * 0.125f;
      }
    }
  }
}

extern "C" void kernel_launch(void* const* d_in, const int* in_sizes, int n_in,
                              void* d_out, int out_size, void* d_ws, size_t ws_size,
                              hipStream_t stream) {
  const float* hs    = (const float*)d_in[0];
  const float* Qt    = (const float*)d_in[1];
  const int*   et    = (const int*)d_in[2];
  const int*   tau   = (const int*)d_in[3];
  const int*   dt    = (const int*)d_in[4];
  const float* emb   = (const float*)d_in[5];
  const float* linW  = (const float*)d_in[6];
  const float* linB  = (const float*)d_in[7];
  const float* KW    = (const float*)d_in[8];
  const float* Kb    = (const float*)d_in[9];
  const float* VW    = (const float*)d_in[10];
  const float* Vb    = (const float*)d_in[11];
  const float* WattW = (const float*)d_in[12];
  const float* WmsgW = (const float*)d_in[13];
  const float* mu    = (const float*)d_in[14];

  char* ws = (char*)d_ws;
  float* R     = (float*)(ws + OFF_R);
  short* Wc    = (short*)(ws + OFF_WC);
  float* biasC = (float*)(ws + OFF_BIAS);
  int*   cnt   = (int*)(ws + OFF_CNT);
  int*   permT = (int*)(ws + OFF_PT);
  int*   permE = (int*)(ws + OFF_PE);
  short* Ks    = (short*)(ws + OFF_KS);

  float* attOut = (float*)d_out;
  float* Mout   = (float*)d_out + (long)E_N * 8;

  hipMemsetAsync(cnt, 0, 64 * sizeof(int), stream);
  hipMemsetAsync(permT, 0xFF, PT * sizeof(int), stream);
  hipMemsetAsync(permE, 0xFF, PE * sizeof(int), stream);

  k_rte<<<240, 256, 0, stream>>>(emb, linW, linB, R);
  k_cvtw<<<2048, 256, 0, stream>>>(KW, VW, Wc);
  k_cvtb<<<16, 256, 0, stream>>>(Kb, Vb, biasC);
  k_hist<<<(E_N + 255) / 256, 256, 0, stream>>>(tau, et, cnt);
  k_bases<<<1, 1, 0, stream>>>(cnt);
  k_scatter<<<(E_N + 255) / 256, 256, 0, stream>>>(tau, et, cnt, permT, permE);
  k_gemm<<<PT / 64, 512, 0, stream>>>(hs, R, dt, tau, Wc, biasC, permT, Ks, Mout);
  k_stage2<<<PE / 64, 512, 0, stream>>>(permE, et, WattW, WmsgW, Qt, mu, Ks, Mout, attOut);
}

// Round 3
// 693.312 us; speedup vs baseline: 2.0963x; 1.1639x over previous
//
#include <hip/hip_runtime.h>
#include <hip/hip_bf16.h>
#include <stdint.h>

#define E_N 150000
#define IN 512
#define MAXLEN 240

// perm sizes: permT 128-aligned per tau type, permE 64-aligned per etype
#define PT 150528   // >= E + 4*127, multiple of 128 (1176 tiles)
#define PE 150528   // >= E + 8*63, multiple of 64  (2352 tiles)
#define NTILE_T 1176

typedef __attribute__((ext_vector_type(8))) short short8;
typedef __attribute__((ext_vector_type(4))) short short4v;
typedef __attribute__((ext_vector_type(4))) float f32x4;

// ---------- ws layout (bytes) ----------
#define OFF_R    0UL                       // float [240][512]      491520
#define OFF_WC   491520UL                  // bf16  [4][1024][512]  4194304
#define OFF_BIAS 4685824UL                 // float [4][1024]       16384
#define OFF_CNT  4702208UL                 // int   [64]            256
#define OFF_PT   4702464UL                 // int   [PT]            602112
#define OFF_PE   5304576UL                 // int   [PE]            602112
#define OFF_KS   5906688UL                 // bf16  [E][512]        153600000
// total ~159.5 MB

static __device__ __forceinline__ short f2bf(float f) {
  union { float f; uint32_t u; } v; v.f = f;
  uint32_t u = v.u;
  uint32_t r = (u + 0x7fffu + ((u >> 16) & 1u)) >> 16;
  return (short)r;
}

// R[p][o] = sum_i emb[p][i]*linW[o][i] + linB[o]
__global__ __launch_bounds__(256) void k_rte(const float* __restrict__ emb,
    const float* __restrict__ linW, const float* __restrict__ linB,
    float* __restrict__ R) {
  __shared__ float x[IN];
  int p = blockIdx.x;
  for (int i = threadIdx.x; i < IN; i += 256) x[i] = emb[p * IN + i];
  __syncthreads();
  for (int o = threadIdx.x; o < IN; o += 256) {
    const float* w = linW + (long)o * IN;
    float s = 0.f;
#pragma unroll 4
    for (int k = 0; k < IN; k += 4) {
      float4 wv = *(const float4*)(w + k);
      s += wv.x * x[k] + wv.y * x[k + 1] + wv.z * x[k + 2] + wv.w * x[k + 3];
    }
    R[p * IN + o] = s + linB[o];
  }
}

// Wc[t][o][k] bf16: o<512 -> K_W[t][o][k], else V_W[t][o-512][k]
__global__ __launch_bounds__(256) void k_cvtw(const float* __restrict__ KW,
    const float* __restrict__ VW, short* __restrict__ Wc) {
  long idx = ((long)blockIdx.x * 256 + threadIdx.x) * 4;  // total 2097152
  int t = (int)(idx >> 19);
  int rem = (int)(idx & ((1 << 19) - 1));
  int o = rem >> 9;
  int k = rem & 511;
  const float* src = (o < 512) ? (KW + ((long)(t * 512 + o) * 512) + k)
                               : (VW + ((long)(t * 512 + (o - 512)) * 512) + k);
  float4 v = *(const float4*)src;
  short4v b;
  b.x = f2bf(v.x); b.y = f2bf(v.y); b.z = f2bf(v.z); b.w = f2bf(v.w);
  *(short4v*)(Wc + idx) = b;
}

__global__ __launch_bounds__(256) void k_cvtb(const float* __restrict__ Kb,
    const float* __restrict__ Vb, float* __restrict__ biasC) {
  int idx = blockIdx.x * 256 + threadIdx.x;  // 4096 total
  int t = idx >> 10;
  int o = idx & 1023;
  biasC[idx] = (o < 512) ? Kb[t * 512 + o] : Vb[t * 512 + (o - 512)];
}

__global__ __launch_bounds__(256) void k_hist(const int* __restrict__ tau,
    const int* __restrict__ et, int* __restrict__ cnt) {
  __shared__ int l[12];
  if (threadIdx.x < 12) l[threadIdx.x] = 0;
  __syncthreads();
  int e = blockIdx.x * 256 + threadIdx.x;
  if (e < E_N) {
    atomicAdd(&l[tau[e]], 1);
    atomicAdd(&l[4 + et[e]], 1);
  }
  __syncthreads();
  if (threadIdx.x < 12) atomicAdd(&cnt[threadIdx.x], l[threadIdx.x]);
}

// c: [0..3]=cnt_tau [4..11]=cnt_et [12..15]=base_tau(128-al) [16..23]=base_et(64-al)
// [24..27]=cur_tau [28..35]=cur_et
__global__ void k_bases(int* c) {
  int b = 0;
  for (int t = 0; t < 4; t++) { c[12 + t] = b; b += ((c[t] + 127) >> 7) << 7; }
  b = 0;
  for (int g = 0; g < 8; g++) { c[16 + g] = b; b += ((c[4 + g] + 63) >> 6) << 6; }
  for (int i = 24; i < 36; i++) c[i] = 0;
}

__global__ __launch_bounds__(256) void k_scatter(const int* __restrict__ tau,
    const int* __restrict__ et, int* __restrict__ c,
    int* __restrict__ permT, int* __restrict__ permE) {
  __shared__ int lc[12], lbase[12];
  if (threadIdx.x < 12) lc[threadIdx.x] = 0;
  __syncthreads();
  int e = blockIdx.x * 256 + threadIdx.x;
  bool v = e < E_N;
  int t = 0, g = 0, pt = 0, pe = 0;
  if (v) {
    t = tau[e]; g = et[e];
    pt = atomicAdd(&lc[t], 1);
    pe = atomicAdd(&lc[4 + g], 1);
  }
  __syncthreads();
  if (threadIdx.x < 12) {
    int n = lc[threadIdx.x];
    int base = 0;
    if (n > 0) {
      if (threadIdx.x < 4) base = atomicAdd(&c[24 + threadIdx.x], n);
      else                 base = atomicAdd(&c[28 + (threadIdx.x - 4)], n);
    }
    lbase[threadIdx.x] = base;
  }
  __syncthreads();
  if (v) {
    permT[c[12 + t] + lbase[t] + pt] = e;
    permE[c[16 + g] + lbase[4 + g] + pe] = e;
  }
}

// h_hat pass: h_hat[e] = bf16(h_s[e] + R[dt[e]]), written into first 1KB of
// edge e's 2KB M-row in d_out. 16 rows/block, 16 threads/row (32 floats each).
__global__ __launch_bounds__(256) void k_hhat(const float* __restrict__ hs,
    const float* __restrict__ R, const int* __restrict__ dt,
    char* __restrict__ out) {
  int tid = threadIdx.x;
  long e = (long)blockIdx.x * 16 + (tid >> 4);
  int sub = tid & 15;  // 32 consecutive floats
  const float* hp = hs + e * 512 + sub * 32;
  const float* rp = R + (long)dt[e] * 512 + sub * 32;
  short* op = (short*)(out + e * 2048) + sub * 32;
#pragma unroll
  for (int j = 0; j < 4; j++) {
    float4 h0 = *(const float4*)(hp + j * 8);
    float4 h1 = *(const float4*)(hp + j * 8 + 4);
    float4 r0 = *(const float4*)(rp + j * 8);
    float4 r1 = *(const float4*)(rp + j * 8 + 4);
    short8 o;
    o[0] = f2bf(h0.x + r0.x); o[1] = f2bf(h0.y + r0.y);
    o[2] = f2bf(h0.z + r0.z); o[3] = f2bf(h0.w + r0.w);
    o[4] = f2bf(h1.x + r1.x); o[5] = f2bf(h1.y + r1.y);
    o[6] = f2bf(h1.z + r1.z); o[7] = f2bf(h1.w + r1.w);
    *(short8*)(op + j * 8) = o;
  }
}

// Stage-1 GEMM, m97-style 128x128 tile, BK=32, 4 waves, global_load_lds both
// operands, XOR chunk swizzle (2-way max on ds_read_b128 = free).
// grid 9408 = 1176 row-tiles x 8 col-tiles; col-tiles 0..3 -> K_s, 4..7 -> V_s.
__global__ __launch_bounds__(256, 4) void k_gemm(
    const char* __restrict__ hhat,   // bf16 rows at hhat + e*2048 (1KB used)
    const int* __restrict__ tau,
    const short* __restrict__ Wc, const float* __restrict__ biasC,
    const int* __restrict__ perm,
    short* __restrict__ Ks, float* Mout) {
  __shared__ short sA[4096];   // [128 rows][32 k] bf16, chunk-swizzled
  __shared__ short sB[4096];   // [128 cols][32 k]
  __shared__ int eRow[128];
  __shared__ int metaT;
  int tid = threadIdx.x;
  // XCD swizzle: 9408 = 8*1176; blocks of one row-tile land on one XCD
  int l = (blockIdx.x & 7) * NTILE_T + (blockIdx.x >> 3);
  int ttile = l >> 3, ctile = l & 7;
  int m0 = ttile * 128;
  if (tid < 128) eRow[tid] = perm[m0 + tid];
  if (tid == 0) {
    int e0 = perm[m0];  // first slot of a non-empty tile is always valid
    metaT = (e0 >= 0) ? tau[e0] : -1;
  }
  __syncthreads();
  int t = metaT;
  if (t < 0) return;
  int n0 = ctile * 128;

  int lane = tid & 63;
  int w = tid >> 6;
  int wm = w >> 1, wn = w & 1;

  // --- staging thread assignment: wave w stages rows/cols [w*32, w*32+32) ---
  int rS = w * 32 + (lane >> 2);
  int cS = lane & 3;                       // chunk' at destination
  int e0r = eRow[rS];      if (e0r < 0) e0r = 0;
  int e1r = eRow[rS + 16]; if (e1r < 0) e1r = 0;
  int ch0 = (cS - (rS >> 1)) & 3;          // inverse swizzle -> source chunk
  int ch1 = (cS - ((rS + 16) >> 1)) & 3;
  const char* srcA0 = hhat + (size_t)e0r * 2048 + ch0 * 16;
  const char* srcA1 = hhat + (size_t)e1r * 2048 + ch1 * 16;
  const char* wcb = (const char*)(Wc + ((size_t)t * 1024 + n0) * 512);
  const char* srcB0 = wcb + (size_t)rS * 1024 + ch0 * 16;
  const char* srcB1 = wcb + (size_t)(rS + 16) * 1024 + ch1 * 16;
  char* dA0 = (char*)sA + w * 2048;
  char* dA1 = (char*)sA + w * 2048 + 1024;
  char* dB0 = (char*)sB + w * 2048;
  char* dB1 = (char*)sB + w * 2048 + 1024;

  // --- fragment read bases (chunk' invariant across mi/ni since +16 rows -> +8 in (row>>1)) ---
  int aRow = wm * 64 + (lane & 15);
  int aOff = aRow * 64 + ((((lane >> 4) + (aRow >> 1)) & 3) << 4);
  int bRow = wn * 64 + (lane & 15);
  int bOff = bRow * 64 + ((((lane >> 4) + (bRow >> 1)) & 3) << 4);

  f32x4 acc[4][4] = {};
#pragma unroll
  for (int kk = 0; kk < 16; kk++) {
    __syncthreads();   // previous iter's reads done before overwrite
    __builtin_amdgcn_global_load_lds((const uint32_t*)(srcA0 + kk * 64), (uint32_t*)dA0, 16, 0, 0);
    __builtin_amdgcn_global_load_lds((const uint32_t*)(srcA1 + kk * 64), (uint32_t*)dA1, 16, 0, 0);
    __builtin_amdgcn_global_load_lds((const uint32_t*)(srcB0 + kk * 64), (uint32_t*)dB0, 16, 0, 0);
    __builtin_amdgcn_global_load_lds((const uint32_t*)(srcB1 + kk * 64), (uint32_t*)dB1, 16, 0, 0);
    __syncthreads();   // compiler drains vmcnt(0) before barrier
    short8 a[4], b[4];
#pragma unroll
    for (int mi = 0; mi < 4; mi++)
      a[mi] = *(const short8*)((const char*)sA + aOff + mi * 1024);
#pragma unroll
    for (int ni = 0; ni < 4; ni++)
      b[ni] = *(const short8*)((const char*)sB + bOff + ni * 1024);
#pragma unroll
    for (int mi = 0; mi < 4; mi++)
#pragma unroll
      for (int ni = 0; ni < 4; ni++)
        acc[mi][ni] = __builtin_amdgcn_mfma_f32_16x16x32_bf16(a[mi], b[ni], acc[mi][ni], 0, 0, 0);
  }

  // epilogue: D row=(lane>>4)*4+reg (A-row), col=lane&15 (B-col)
  int l15 = lane & 15;
  int rbase = (lane >> 4) * 4;
  bool isK = ctile < 4;
  float bias[4];
#pragma unroll
  for (int ni = 0; ni < 4; ni++)
    bias[ni] = biasC[t * 1024 + n0 + wn * 64 + ni * 16 + l15];
#pragma unroll
  for (int mi = 0; mi < 4; mi++) {
#pragma unroll
    for (int r = 0; r < 4; r++) {
      int row = wm * 64 + mi * 16 + rbase + r;
      int e = eRow[row];
      if (e < 0) continue;
      if (isK) {
        short* kd = Ks + (size_t)e * 512 + n0 + wn * 64;
#pragma unroll
        for (int ni = 0; ni < 4; ni++)
          kd[ni * 16 + l15] = f2bf(acc[mi][ni][r] + bias[ni]);
      } else {
        short* vd = (short*)((char*)Mout + (size_t)e * 2048 + 1024) + (n0 - 512) + wn * 64;
#pragma unroll
        for (int ni = 0; ni < 4; ni++)
          vd[ni * 16 + l15] = f2bf(acc[mi][ni][r] + bias[ni]);
      }
    }
  }
}

// k_msg: M = V_s @ Wmsg[g]^T  (V bf16 in-place in d_out M rows; writes f32 M)
__global__ __launch_bounds__(512, 1) void k_msg(
    const int* __restrict__ perm, const int* __restrict__ et,
    const float* __restrict__ WmsgW, float* Mout) {
  __shared__ short Wm[64][68];
  __shared__ int eArr[64];
  __shared__ int metaG;
  int tid = threadIdx.x;
  int m0 = blockIdx.x * 64;
  if (tid < 64) eArr[tid] = perm[m0 + tid];
  if (tid == 0) {
    int e0 = perm[m0];
    metaG = (e0 >= 0) ? et[e0] : -1;
  }
  __syncthreads();
  int g = metaG;
  if (g < 0) return;
  for (int i = tid; i < 4096; i += 512)
    Wm[i >> 6][i & 63] = f2bf(WmsgW[(long)g * 4096 + i]);
  __syncthreads();

  int lane = tid & 63;
  int wv = tid >> 6;
  int wvBase = wv * 64;
  int l15 = lane & 15;
  int lk8 = (lane >> 4) * 8;
  int rbase = (lane >> 4) * 4;

  short8 av[4][2];
#pragma unroll
  for (int mi = 0; mi < 4; mi++) {
    int lr = wvBase + mi * 16 + l15;
    int e = eArr[lr >> 3]; if (e < 0) e = 0;
    const short* vp = (const short*)((const char*)Mout + (size_t)e * 2048 + 1024)
                      + (lr & 7) * 64 + lk8;
    av[mi][0] = *(const short8*)vp;
    av[mi][1] = *(const short8*)(vp + 32);
  }
  short8 bm[4][2];
#pragma unroll
  for (int ni = 0; ni < 4; ni++)
#pragma unroll
    for (int kk = 0; kk < 2; kk++)
      bm[ni][kk] = *(const short8*)&Wm[ni * 16 + l15][kk * 32 + lk8];
  f32x4 accM[4][4] = {};
#pragma unroll
  for (int kk = 0; kk < 2; kk++)
#pragma unroll
    for (int mi = 0; mi < 4; mi++)
#pragma unroll
      for (int ni = 0; ni < 4; ni++)
        accM[mi][ni] = __builtin_amdgcn_mfma_f32_16x16x32_bf16(av[mi][kk], bm[ni][kk], accM[mi][ni], 0, 0, 0);
#pragma unroll
  for (int mi = 0; mi < 4; mi++) {
#pragma unroll
    for (int r = 0; r < 4; r++) {
      int lr = wvBase + mi * 16 + rbase + r;
      int e = eArr[lr >> 3];
      if (e < 0) continue;
      int h = lr & 7;
#pragma unroll
      for (int ni = 0; ni < 4; ni++)
        Mout[(long)e * 512 + h * 64 + ni * 16 + l15] = accM[mi][ni][r];
    }
  }
}

// k_att: attk = K_s @ Watt[g]^T ; att = (Q . attk) * mu / 8
__global__ __launch_bounds__(512, 1) void k_att(
    const int* __restrict__ perm, const int* __restrict__ et,
    const float* __restrict__ WattW, const float* __restrict__ Qt,
    const float* __restrict__ mu, const short* __restrict__ Ks,
    float* __restrict__ attOut) {
  __shared__ short Wa[64][68];
  __shared__ float muL[8];
  __shared__ int eArr[64];
  __shared__ int metaG;
  int tid = threadIdx.x;
  int m0 = blockIdx.x * 64;
  if (tid < 64) eArr[tid] = perm[m0 + tid];
  if (tid == 0) {
    int e0 = perm[m0];
    metaG = (e0 >= 0) ? et[e0] : -1;
  }
  __syncthreads();
  int g = metaG;
  if (g < 0) return;
  for (int i = tid; i < 4096; i += 512)
    Wa[i >> 6][i & 63] = f2bf(WattW[(long)g * 4096 + i]);
  if (tid < 8) muL[tid] = mu[g * 8 + tid];
  __syncthreads();

  int lane = tid & 63;
  int wv = tid >> 6;
  int wvBase = wv * 64;
  int l15 = lane & 15;
  int lk8 = (lane >> 4) * 8;
  int rbase = (lane >> 4) * 4;

  short8 ak[4][2];
#pragma unroll
  for (int mi = 0; mi < 4; mi++) {
    int lr = wvBase + mi * 16 + l15;
    int e = eArr[lr >> 3]; if (e < 0) e = 0;
    const short* kp = Ks + (size_t)e * 512 + (lr & 7) * 64 + lk8;
    ak[mi][0] = *(const short8*)kp;
    ak[mi][1] = *(const short8*)(kp + 32);
  }
  short8 ba[4][2];
#pragma unroll
  for (int ni = 0; ni < 4; ni++)
#pragma unroll
    for (int kk = 0; kk < 2; kk++)
      ba[ni][kk] = *(const short8*)&Wa[ni * 16 + l15][kk * 32 + lk8];
  f32x4 accA[4][4] = {};
#pragma unroll
  for (int kk = 0; kk < 2; kk++)
#pragma unroll
    for (int mi = 0; mi < 4; mi++)
#pragma unroll
      for (int ni = 0; ni < 4; ni++)
        accA[mi][ni] = __builtin_amdgcn_mfma_f32_16x16x32_bf16(ak[mi][kk], ba[ni][kk], accA[mi][ni], 0, 0, 0);
#pragma unroll
  for (int mi = 0; mi < 4; mi++) {
#pragma unroll
    for (int r = 0; r < 4; r++) {
      int lr = wvBase + mi * 16 + rbase + r;
      int e = eArr[lr >> 3];
      if (e < 0) continue;
      int h = lr & 7;
      const float* qp = Qt + ((long)e * 8 + h) * 64 + l15;
      float s = 0.f;
#pragma unroll
      for (int ni = 0; ni < 4; ni++)
        s += qp[ni * 16] * accA[mi][ni][r];
      s += __shfl_xor(s, 1);
      s += __shfl_xor(s, 2);
      s += __shfl_xor(s, 4);
      s += __shfl_xor(s, 8);
      if (l15 == 0) attOut[(long)e * 8 + h] = s * muL[h] * 0.125f;
    }
  }
}

extern "C" void kernel_launch(void* const* d_in, const int* in_sizes, int n_in,
                              void* d_out, int out_size, void* d_ws, size_t ws_size,
                              hipStream_t stream) {
  const float* hs    = (const float*)d_in[0];
  const float* Qt    = (const float*)d_in[1];
  const int*   et    = (const int*)d_in[2];
  const int*   tau   = (const int*)d_in[3];
  const int*   dt    = (const int*)d_in[4];
  const float* emb   = (const float*)d_in[5];
  const float* linW  = (const float*)d_in[6];
  const float* linB  = (const float*)d_in[7];
  const float* KW    = (const float*)d_in[8];
  const float* Kb    = (const float*)d_in[9];
  const float* VW    = (const float*)d_in[10];
  const float* Vb    = (const float*)d_in[11];
  const float* WattW = (const float*)d_in[12];
  const float* WmsgW = (const float*)d_in[13];
  const float* mu    = (const float*)d_in[14];

  char* ws = (char*)d_ws;
  float* R     = (float*)(ws + OFF_R);
  short* Wc    = (short*)(ws + OFF_WC);
  float* biasC = (float*)(ws + OFF_BIAS);
  int*   cnt   = (int*)(ws + OFF_CNT);
  int*   permT = (int*)(ws + OFF_PT);
  int*   permE = (int*)(ws + OFF_PE);
  short* Ks    = (short*)(ws + OFF_KS);

  float* attOut = (float*)d_out;
  float* Mout   = (float*)d_out + (long)E_N * 8;

  hipMemsetAsync(cnt, 0, 64 * sizeof(int), stream);
  hipMemsetAsync(permT, 0xFF, PT * sizeof(int), stream);
  hipMemsetAsync(permE, 0xFF, PE * sizeof(int), stream);

  k_rte<<<240, 256, 0, stream>>>(emb, linW, linB, R);
  k_cvtw<<<2048, 256, 0, stream>>>(KW, VW, Wc);
  k_cvtb<<<16, 256, 0, stream>>>(Kb, Vb, biasC);
  k_hist<<<(E_N + 255) / 256, 256, 0, stream>>>(tau, et, cnt);
  k_bases<<<1, 1, 0, stream>>>(cnt);
  k_scatter<<<(E_N + 255) / 256, 256, 0, stream>>>(tau, et, cnt, permT, permE);
  k_hhat<<<E_N / 16, 256, 0, stream>>>(hs, R, dt, (char*)Mout);
  k_gemm<<<NTILE_T * 8, 256, 0, stream>>>((const char*)Mout, tau, Wc, biasC, permT, Ks, Mout);
  k_msg<<<PE / 64, 512, 0, stream>>>(permE, et, WmsgW, Mout);
  k_att<<<PE / 64, 512, 0, stream>>>(permE, et, WattW, Qt, mu, Ks, attOut);
}